// Round 15
// baseline (402.580 us; speedup 1.0000x reference)
//
#include <hip/hip_runtime.h>

#define BATCH    4096
#define SENS     64
#define UNITS    128
#define MOTOR_N  32
#define UNFOLDS  6
#define NB       4               // batch rows per inner pass
#define ROWS_PER_BLOCK 8
#define NBLOCKS  (BATCH / ROWS_PER_BLOCK)   // 512 -> 2 blocks/CU
#define NGROUPS  (ROWS_PER_BLOCK / NB)      // 2

#define LOG2E 1.4426950408889634f

__device__ __forceinline__ float fast_exp2(float x) { return __builtin_amdgcn_exp2f(x); }
__device__ __forceinline__ float fast_rcp(float x)  { return __builtin_amdgcn_rcpf(x); }

// ---------------------------------------------------------------------------
// Fused LTC cell (r12 structure, doubled grid).
//
// ROUND-13 LESSON: the backend consistently budgets ~60-64 VGPR for
// 1024-thread blocks (sized for 8 waves/EU = 2 blocks/CU), but a 256-block
// grid on 256 CUs can only place 1 block/CU (45% occupancy). Launch 512
// blocks (ROWS_PER_BLOCK=8) so the 2-blocks/CU the allocator sized for
// actually materializes. launch_bounds(1024,8) matches that budget;
// waves_per_eu clamp removed (it forbade 2 blocks/CU).
// ---------------------------------------------------------------------------
__global__ __launch_bounds__(1024, 8)
void ltc_fused(
    const float* __restrict__ inputs,  const float* __restrict__ state,
    const float* __restrict__ gleak,   const float* __restrict__ vleak,
    const float* __restrict__ cm,
    const float* __restrict__ sigma,   const float* __restrict__ mu,
    const float* __restrict__ w,       const float* __restrict__ erev,
    const float* __restrict__ s_sigma, const float* __restrict__ s_mu,
    const float* __restrict__ s_w,     const float* __restrict__ s_erev,
    const float* __restrict__ input_w, const float* __restrict__ input_b,
    const float* __restrict__ output_w,const float* __restrict__ output_b,
    const int*   __restrict__ mask,    const int* __restrict__ s_mask,
    float* __restrict__ out, float* __restrict__ next_state)
{
    __shared__ float x_lds[NB][SENS];
    __shared__ float v_lds[NB][UNITS];
    __shared__ float pn[NB][8][UNITS];
    __shared__ float pd[NB][8][UNITS];

    const int t = threadIdx.x;
    const int u = t & (UNITS - 1);
    const int c = t >> 7;            // 0..7

    // ---- recurrent params: 16 synapses/thread ----
    float rgl[16], rgb[16], rws[16];
#pragma unroll
    for (int k = 0; k < 16; ++k) {
        int idx = (c * 16 + k) * UNITS + u;
        float sg = sigma[idx] * LOG2E;
        float wv = w[idx] * (mask[idx] != 0 ? 1.0f : 0.0f);
        rgl[k] = -sg;                 // z = rgl*v + rgb = -sg*(v - mu)
        rgb[k] = sg * mu[idx];
        rws[k] = wv * erev[idx];      // |rws| == wv  (erev = +-1)
    }
    // ---- sensory params: 8 synapses/thread ----
    float sgl[8], sgb[8], sws[8];
#pragma unroll
    for (int j = 0; j < 8; ++j) {
        int idx = (c * 8 + j) * UNITS + u;
        float sg = s_sigma[idx] * LOG2E;
        float wv = s_w[idx] * (s_mask[idx] != 0 ? 1.0f : 0.0f);
        sgl[j] = -sg;
        sgb[j] = sg * s_mu[idx];
        sws[j] = wv * s_erev[idx];
    }
    // Pin: make each param the output of an opaque op -> no remat/reload.
#pragma unroll
    for (int k = 0; k < 16; ++k)
        asm volatile("" : "+v"(rgl[k]), "+v"(rgb[k]), "+v"(rws[k]));
#pragma unroll
    for (int j = 0; j < 8; ++j)
        asm volatile("" : "+v"(sgl[j]), "+v"(sgb[j]), "+v"(sws[j]));

    // reduction-thread constants
    const bool red = (t < NB * UNITS);   // first 512 threads
    const int  rb  = t >> 7;             // 0..3 when red
    const int  ru  = u;
    const float cmt = cm[ru] * 6.0f;
    const float nb0 = gleak[ru] * vleak[ru];
    const float db0 = cmt + gleak[ru] + 1e-8f;

    for (int g = 0; g < NGROUPS; ++g) {
        const int b0 = blockIdx.x * ROWS_PER_BLOCK + g * NB;

        if (t < NB * SENS) {             // stage x = inputs*input_w + input_b
            int b = t >> 6, s = t & 63;
            x_lds[b][s] = inputs[(b0 + b) * SENS + s] * input_w[s] + input_b[s];
        }
        float vcur = 0.f, nbase = 0.f, dbase = 0.f;
        if (red) {
            vcur = state[(b0 + rb) * UNITS + ru];
            v_lds[rb][ru] = vcur;
        }
        __syncthreads();

        // ---- sensory phase: partials into pn/pd ----
#pragma unroll 1
        for (int b = 0; b < NB; ++b) {
            float n = 0.f, d = 0.f;
            const float4* xp = (const float4*)&x_lds[b][c * 8];
            float4 xa = xp[0], xb = xp[1];
            float xs[8] = {xa.x, xa.y, xa.z, xa.w, xb.x, xb.y, xb.z, xb.w};
#pragma unroll
            for (int j = 0; j < 8; ++j) {
                float e = fast_exp2(fmaf(sgl[j], xs[j], sgb[j]));
                float r = fast_rcp(1.0f + e);
                n = fmaf(sws[j], r, n);
                d = fmaf(fabsf(sws[j]), r, d);
            }
            pn[b][c][u] = n;
            pd[b][c][u] = d;
        }
        __syncthreads();

        if (red) {
            float n = nb0, d = db0;
#pragma unroll
            for (int cc = 0; cc < 8; ++cc) {
                n += pn[rb][cc][ru];
                d += pd[rb][cc][ru];
            }
            nbase = n; dbase = d;
        }
        __syncthreads();   // partials consumed before step-loop overwrites

        // ---- 6 ODE unfolds ----
#pragma unroll 1
        for (int step = 0; step < UNFOLDS; ++step) {
#pragma unroll 1
            for (int b = 0; b < NB; ++b) {
                float n = 0.f, d = 0.f;
                const float4* vp = (const float4*)&v_lds[b][c * 16];
#pragma unroll
                for (int q = 0; q < 4; ++q) {
                    float4 v4 = vp[q];
                    const float* vf = (const float*)&v4;
#pragma unroll
                    for (int jj = 0; jj < 4; ++jj) {
                        int k = q * 4 + jj;
                        float e = fast_exp2(fmaf(rgl[k], vf[jj], rgb[k]));
                        float r = fast_rcp(1.0f + e);
                        n = fmaf(rws[k], r, n);
                        d = fmaf(fabsf(rws[k]), r, d);
                    }
                }
                pn[b][c][u] = n;
                pd[b][c][u] = d;
            }
            __syncthreads();

            if (red) {
                float n = nbase, d = dbase;
#pragma unroll
                for (int cc = 0; cc < 8; ++cc) {
                    n += pn[rb][cc][ru];
                    d += pd[rb][cc][ru];
                }
                vcur = fmaf(cmt, vcur, n) * fast_rcp(d);
                v_lds[rb][ru] = vcur;
            }
            __syncthreads();
        }

        if (red) {
            int row = b0 + rb;
            next_state[row * UNITS + ru] = vcur;
            if (ru < MOTOR_N)
                out[row * MOTOR_N + ru] = vcur * output_w[ru] + output_b[ru];
        }
        __syncthreads();   // protect v_lds/x_lds before next group's writes
    }
}

// ---------------------------------------------------------------------------
extern "C" void kernel_launch(void* const* d_in, const int* in_sizes, int n_in,
                              void* d_out, int out_size, void* d_ws, size_t ws_size,
                              hipStream_t stream) {
    const float* inputs   = (const float*)d_in[0];
    const float* state    = (const float*)d_in[1];
    const float* gleak    = (const float*)d_in[2];
    const float* vleak    = (const float*)d_in[3];
    const float* cm       = (const float*)d_in[4];
    const float* sigma    = (const float*)d_in[5];
    const float* mu       = (const float*)d_in[6];
    const float* w        = (const float*)d_in[7];
    const float* erev     = (const float*)d_in[8];
    const float* s_sigma  = (const float*)d_in[9];
    const float* s_mu     = (const float*)d_in[10];
    const float* s_w      = (const float*)d_in[11];
    const float* s_erev   = (const float*)d_in[12];
    const float* input_w  = (const float*)d_in[13];
    const float* input_b  = (const float*)d_in[14];
    const float* output_w = (const float*)d_in[15];
    const float* output_b = (const float*)d_in[16];
    const int*   mask     = (const int*)d_in[17];
    const int*   s_mask   = (const int*)d_in[18];

    float* out        = (float*)d_out;                   // [B, 32]
    float* next_state = out + (size_t)BATCH * MOTOR_N;   // [B, 128]

    ltc_fused<<<NBLOCKS, 1024, 0, stream>>>(
        inputs, state, gleak, vleak, cm, sigma, mu, w, erev,
        s_sigma, s_mu, s_w, s_erev, input_w, input_b, output_w, output_b,
        mask, s_mask, out, next_state);
}

// Round 16
// 244.412 us; speedup vs baseline: 1.6471x; 1.6471x over previous
//
#include <hip/hip_runtime.h>

#define BATCH    4096
#define SENS     64
#define UNITS    128
#define MOTOR_N  32
#define UNFOLDS  6
#define NB       4
#define ROWS_PER_BLOCK 8
#define NBLOCKS  (BATCH / ROWS_PER_BLOCK)   // 512 -> 2 blocks/CU
#define NGROUPS  (ROWS_PER_BLOCK / NB)      // 2

#define LOG2E 1.4426950408889634f

__device__ __forceinline__ float fast_exp2(float x) { return __builtin_amdgcn_exp2f(x); }
__device__ __forceinline__ float fast_rcp(float x)  { return __builtin_amdgcn_rcpf(x); }
__device__ __forceinline__ unsigned f2bf(float x) {          // f32 -> bf16 bits (RNE)
    unsigned v = __float_as_uint(x);
    v += 0x7fffu + ((v >> 16) & 1u);
    return v >> 16;
}
__device__ __forceinline__ float bf_lo(unsigned p) { return __uint_as_float(p << 16); }
__device__ __forceinline__ float bf_hi(unsigned p) { return __uint_as_float(p & 0xffff0000u); }

// padded indices: spread each 16-float (v) / 8-float (x) chunk across banks
__device__ __forceinline__ int vpad(int j) { return j + ((j >> 4) << 2); }  // +4 per 16
#define VROW 156   // vpad(127)=155
__device__ __forceinline__ int xpad(int j) { return j + ((j >> 3) << 2); }  // +4 per 8
#define XROW 92    // xpad(63)=91

// full-rate DPP add over 8-lane groups (quad xor1, xor2, half-row mirror)
template <int CTRL>
__device__ __forceinline__ float dpp_add(float x) {
    int s = __builtin_amdgcn_update_dpp(0, __float_as_int(x), CTRL, 0xf, 0xf, true);
    return x + __int_as_float(s);
}
__device__ __forceinline__ float reduce8(float x) {
    x = dpp_add<0xB1>(x);    // quad_perm [1,0,3,2]
    x = dpp_add<0x4E>(x);    // quad_perm [2,3,0,1]
    x = dpp_add<0x141>(x);   // row_half_mirror (lane i <-> 7-i within 8)
    return x;
}

// ---------------------------------------------------------------------------
// Fused LTC, wave-local reduction edition.
// ROUND-15 LESSON: every 1024-thr config gets a ~64-VGPR budget; launch_bounds
// min-waves=8 halved it to 32 -> total param spill -> 1.3 GB scratch traffic,
// 328us. Fit the budget instead: u=t>>3,c=t&7 puts a unit's 8 chunks in 8
// ADJACENT LANES -> chunk reduce = 3 DPP adds (full-rate VALU), killing the
// pn/pd LDS round-trip and halving barriers (1/step). Params: rgl/rgb f32
// (32 regs, exp2-sensitive) + rws bf16-packed (8 regs) = 40 pinned, ~56 peak.
// LDS ~16KB, 512 blocks -> 2 blocks/CU.
// ---------------------------------------------------------------------------
__global__ __launch_bounds__(1024)
void ltc_fused(
    const float* __restrict__ inputs,  const float* __restrict__ state,
    const float* __restrict__ gleak,   const float* __restrict__ vleak,
    const float* __restrict__ cm,
    const float* __restrict__ sigma,   const float* __restrict__ mu,
    const float* __restrict__ w,       const float* __restrict__ erev,
    const float* __restrict__ s_sigma, const float* __restrict__ s_mu,
    const float* __restrict__ s_w,     const float* __restrict__ s_erev,
    const float* __restrict__ input_w, const float* __restrict__ input_b,
    const float* __restrict__ output_w,const float* __restrict__ output_b,
    const int*   __restrict__ mask,    const int* __restrict__ s_mask,
    float* __restrict__ out, float* __restrict__ next_state)
{
    __shared__ __align__(16) float x_lds[ROWS_PER_BLOCK][XROW];
    __shared__ float nb_lds[ROWS_PER_BLOCK][UNITS];
    __shared__ float db_lds[ROWS_PER_BLOCK][UNITS];
    __shared__ __align__(16) float v_lds[2][NB][VROW];

    const int t = threadIdx.x;
    const int u = t >> 3;            // 0..127 (8 adjacent lanes share u)
    const int c = t & 7;             // chunk 0..7
    const int vbase = c * 20;        // vpad(c*16)
    const int xbase = c * 12;        // xpad(c*8)

    const float cmt = cm[u] * 6.0f;
    const float glv = gleak[u];
    const float nb0 = glv * vleak[u];
    const float db0 = cmt + glv + 1e-8f;

    // stage x = inputs*input_w + input_b  (all 8 rows of this block)
    if (t < ROWS_PER_BLOCK * SENS) {
        int r = t >> 6, s = t & 63;
        x_lds[r][xpad(s)] =
            inputs[(blockIdx.x * ROWS_PER_BLOCK + r) * SENS + s] * input_w[s] + input_b[s];
    }

    // ---- sensory params (transient, f32): 8 syn/thread ----
    float sgl[8], sgb[8], sws[8];
#pragma unroll
    for (int k = 0; k < 8; ++k) {
        int idx = (c * 8 + k) * UNITS + u;
        float sg = s_sigma[idx] * LOG2E;
        float wv = s_w[idx] * (s_mask[idx] != 0 ? 1.0f : 0.0f);
        sgl[k] = -sg;
        sgb[k] = sg * s_mu[idx];
        sws[k] = wv * s_erev[idx];
    }
    __syncthreads();                 // x_lds ready

    // ---- sensory phase: nb/db per (row, u), DPP-reduced in-wave ----
#pragma unroll 1
    for (int row = 0; row < ROWS_PER_BLOCK; ++row) {
        const float4* xp = (const float4*)&x_lds[row][xbase];
        float4 xa = xp[0], xb2 = xp[1];
        float xs[8] = {xa.x, xa.y, xa.z, xa.w, xb2.x, xb2.y, xb2.z, xb2.w};
        float n = 0.f, d = 0.f;
#pragma unroll
        for (int k = 0; k < 8; ++k) {
            float e = fast_exp2(fmaf(sgl[k], xs[k], sgb[k]));
            float r = fast_rcp(1.0f + e);
            n = fmaf(sws[k], r, n);
            d = fmaf(fabsf(sws[k]), r, d);
        }
        n = reduce8(n);
        d = reduce8(d);
        if (c == 0) {
            nb_lds[row][u] = nb0 + n;
            db_lds[row][u] = db0 + d;
        }
    }

    // ---- recurrent params: rgl/rgb f32, rws bf16-packed; pinned ----
    float rgl[16], rgb[16];
    unsigned rwsp[8];
#pragma unroll
    for (int k2 = 0; k2 < 8; ++k2) {
        float wt[2];
#pragma unroll
        for (int e2 = 0; e2 < 2; ++e2) {
            int k = k2 * 2 + e2;
            int idx = (c * 16 + k) * UNITS + u;
            float sg = sigma[idx] * LOG2E;
            float wv = w[idx] * (mask[idx] != 0 ? 1.0f : 0.0f);
            rgl[k] = -sg;
            rgb[k] = sg * mu[idx];
            wt[e2] = wv * erev[idx];
        }
        rwsp[k2] = (f2bf(wt[1]) << 16) | f2bf(wt[0]);
    }
#pragma unroll
    for (int k = 0; k < 16; ++k) asm volatile("" : "+v"(rgl[k]), "+v"(rgb[k]));
#pragma unroll
    for (int k2 = 0; k2 < 8; ++k2) asm volatile("" : "+v"(rwsp[k2]));

    // ---- 2 groups x 6 ODE unfolds, double-buffered v, 1 barrier/step ----
#pragma unroll 1
    for (int g = 0; g < NGROUPS; ++g) {
        const int b0 = blockIdx.x * ROWS_PER_BLOCK + g * NB;
        if (t < NB * UNITS) {
            int b = t >> 7, j = t & 127;
            v_lds[0][b][vpad(j)] = state[(b0 + b) * UNITS + j];
        }
        __syncthreads();             // v ready (also fences prev group's LDS use)

        float vc[NB];
#pragma unroll
        for (int b = 0; b < NB; ++b) vc[b] = v_lds[0][b][vpad(u)];

        int p = 0;
#pragma unroll 1
        for (int step = 0; step < UNFOLDS; ++step) {
#pragma unroll
            for (int b = 0; b < NB; ++b) {
                const float4* vp4 = (const float4*)&v_lds[p][b][vbase];
                float n = 0.f, d = 0.f;
#pragma unroll
                for (int h = 0; h < 2; ++h) {          // 2 batches of 8 syn
                    float4 va = vp4[h * 2], vb = vp4[h * 2 + 1];
                    float vf[8] = {va.x, va.y, va.z, va.w, vb.x, vb.y, vb.z, vb.w};
#pragma unroll
                    for (int jj = 0; jj < 8; ++jj) {
                        int k = h * 8 + jj;
                        float e  = fast_exp2(fmaf(rgl[k], vf[jj], rgb[k]));
                        float r  = fast_rcp(1.0f + e);
                        float ws = (k & 1) ? bf_hi(rwsp[k >> 1]) : bf_lo(rwsp[k >> 1]);
                        n = fmaf(ws, r, n);
                        d = fmaf(fabsf(ws), r, d);
                    }
                }
                n = reduce8(n);
                d = reduce8(d);
                const int row = g * NB + b;
                float vnew = fmaf(cmt, vc[b], n + nb_lds[row][u])
                           * fast_rcp(d + db_lds[row][u]);
                vc[b] = vnew;
                if (c == 0) v_lds[p ^ 1][b][vpad(u)] = vnew;
            }
            __syncthreads();
            p ^= 1;
        }

        if (c == 0) {
#pragma unroll
            for (int b = 0; b < NB; ++b) {
                const int row = b0 + b;
                next_state[row * UNITS + u] = vc[b];
                if (u < MOTOR_N)
                    out[row * MOTOR_N + u] = vc[b] * output_w[u] + output_b[u];
            }
        }
    }
}

// ---------------------------------------------------------------------------
extern "C" void kernel_launch(void* const* d_in, const int* in_sizes, int n_in,
                              void* d_out, int out_size, void* d_ws, size_t ws_size,
                              hipStream_t stream) {
    const float* inputs   = (const float*)d_in[0];
    const float* state    = (const float*)d_in[1];
    const float* gleak    = (const float*)d_in[2];
    const float* vleak    = (const float*)d_in[3];
    const float* cm       = (const float*)d_in[4];
    const float* sigma    = (const float*)d_in[5];
    const float* mu       = (const float*)d_in[6];
    const float* w        = (const float*)d_in[7];
    const float* erev     = (const float*)d_in[8];
    const float* s_sigma  = (const float*)d_in[9];
    const float* s_mu     = (const float*)d_in[10];
    const float* s_w      = (const float*)d_in[11];
    const float* s_erev   = (const float*)d_in[12];
    const float* input_w  = (const float*)d_in[13];
    const float* input_b  = (const float*)d_in[14];
    const float* output_w = (const float*)d_in[15];
    const float* output_b = (const float*)d_in[16];
    const int*   mask     = (const int*)d_in[17];
    const int*   s_mask   = (const int*)d_in[18];

    float* out        = (float*)d_out;                   // [B, 32]
    float* next_state = out + (size_t)BATCH * MOTOR_N;   // [B, 128]

    ltc_fused<<<NBLOCKS, 1024, 0, stream>>>(
        inputs, state, gleak, vleak, cm, sigma, mu, w, erev,
        s_sigma, s_mu, s_w, s_erev, input_w, input_b, output_w, output_b,
        mask, s_mask, out, next_state);
}